// Round 3
// baseline (250.473 us; speedup 1.0000x reference)
//
#include <hip/hip_runtime.h>
#include <hip/hip_bf16.h>

#define INPUT_DIM 2048
#define EMBED_DIM 128
#define NROWS 16384

typedef __bf16 bf16x8 __attribute__((ext_vector_type(8)));
typedef float f32x4 __attribute__((ext_vector_type(4)));

__device__ inline float dot4(f32x4 a, f32x4 b) {
    return a.x * b.x + a.y * b.y + a.z * b.z + a.w * b.w;
}

// ---- prep: Vt[n][k] = (bf16)V[k][n] (128x2048 bf16), s[k] = sum_n V[k][n]^2.
// Coalesced both ways via LDS transpose tile (old version did 16B stores at
// 4KB stride = 64 lines per wave-store).
__global__ __launch_bounds__(256) void fm_prep(const float* __restrict__ V,
                                               __bf16* __restrict__ Vt,
                                               float* __restrict__ s) {
    __shared__ float tile[64][132];   // +4 pad: transpose reads 2-way (free, m136)
    const int t = threadIdx.x;
    const int k0 = blockIdx.x * 64;   // grid = 32 blocks

#pragma unroll
    for (int i = 0; i < 8; ++i) {
        int idx = i * 256 + t;        // f32x4 granule 0..2047
        int kk = idx >> 5;            // 0..63
        int nq = (idx & 31) * 4;      // 0..124
        *(f32x4*)&tile[kk][nq] = *(const f32x4*)(V + (size_t)(k0 + kk) * EMBED_DIM + nq);
    }
    __syncthreads();

    // transpose-write: thread -> n = t>>1, k-half = (t&1)*32; pair writes 128B contiguous
    {
        const int n = t >> 1;
        const int ks = (t & 1) * 32;
        __bf16 ov[32];
#pragma unroll
        for (int j = 0; j < 32; ++j) ov[j] = (__bf16)tile[ks + j][n];
#pragma unroll
        for (int q = 0; q < 4; ++q)
            *(bf16x8*)(Vt + (size_t)n * INPUT_DIM + k0 + ks + q * 8) = *(bf16x8*)&ov[q * 8];
    }

    if (t < 64) {
        float a = 0.f;
#pragma unroll
        for (int n4 = 0; n4 < 32; ++n4) {
            f32x4 v = *(f32x4*)&tile[t][n4 * 4];
            a += dot4(v, v);
        }
        s[k0 + t] = a;
    }
}

// ---- main: per block = 16 rows, 4 waves K-split (512 k each).
// R2 fix: VGPR 52 had forced serial {load vb -> vmcnt(0) -> MFMA} chains
// (8 x 200cy L2 round-trips per step = the 99us). Now: all 8 B-frags in
// named regs, all loads issued before MFMAs, next-step x prefetched so the
// HBM stream stays in flight across the MFMA phase. launch_bounds(256,3)
// allows <=168 VGPR -> 12 waves/CU, ~24KB x in flight/CU (> 9.2KB for BW).
__global__ __launch_bounds__(256, 3) void fm_main(const float* __restrict__ x,
                                                  const float* __restrict__ W,
                                                  const float* __restrict__ bptr,
                                                  const __bf16* __restrict__ Vt,
                                                  const float* __restrict__ s,
                                                  float* __restrict__ out) {
    __shared__ __align__(16) float acc_lds[4][16][132];
    __shared__ float lin_lds[4][16];
    __shared__ float sq_lds[4][16];

    const int tid = threadIdx.x;
    const int w = tid >> 6;     // wave id: k-split index
    const int l = tid & 63;
    const int lr = l & 15;      // A row / B col within 16
    const int lg = l >> 4;      // k-group within fragment

    const int row0 = blockIdx.x * 16;
    const int k0 = w * 512;

    const float* xp = x + (size_t)(row0 + lr) * INPUT_DIM + k0 + lg * 8;
    const float* wp = W + k0 + lg * 8;
    const float* sp = s + k0 + lg * 8;
    const __bf16* vtp = Vt + (size_t)lr * INPUT_DIM + k0 + lg * 8;

    f32x4 acc[8];
#pragma unroll
    for (int c = 0; c < 8; ++c) acc[c] = (f32x4){0.f, 0.f, 0.f, 0.f};
    float lin = 0.f, sq = 0.f;

    f32x4 ca0 = *(const f32x4*)xp;
    f32x4 ca1 = *(const f32x4*)(xp + 4);

#pragma unroll 4
    for (int step = 0; step < 16; ++step) {
        // next-step x prefetch (stays outstanding across this step's MFMAs)
        f32x4 na0 = ca0, na1 = ca1;
        if (step < 15) {
            na0 = *(const f32x4*)(xp + 32);
            na1 = *(const f32x4*)(xp + 36);
        }
        // all 8 B-frags issued up front, named regs (no register recycling)
        bf16x8 vb0 = *(const bf16x8*)(vtp + 0 * 16 * INPUT_DIM);
        bf16x8 vb1 = *(const bf16x8*)(vtp + 1 * 16 * INPUT_DIM);
        bf16x8 vb2 = *(const bf16x8*)(vtp + 2 * 16 * INPUT_DIM);
        bf16x8 vb3 = *(const bf16x8*)(vtp + 3 * 16 * INPUT_DIM);
        bf16x8 vb4 = *(const bf16x8*)(vtp + 4 * 16 * INPUT_DIM);
        bf16x8 vb5 = *(const bf16x8*)(vtp + 5 * 16 * INPUT_DIM);
        bf16x8 vb6 = *(const bf16x8*)(vtp + 6 * 16 * INPUT_DIM);
        bf16x8 vb7 = *(const bf16x8*)(vtp + 7 * 16 * INPUT_DIM);
        f32x4 w0 = *(const f32x4*)wp;
        f32x4 w1 = *(const f32x4*)(wp + 4);
        f32x4 s0 = *(const f32x4*)sp;
        f32x4 s1 = *(const f32x4*)(sp + 4);

        // VALU work on current x while Vt loads are in flight
        lin += dot4(ca0, w0) + dot4(ca1, w1);
        sq += dot4(ca0 * ca0, s0) + dot4(ca1 * ca1, s1);

        bf16x8 af;
        af[0] = (__bf16)ca0.x; af[1] = (__bf16)ca0.y;
        af[2] = (__bf16)ca0.z; af[3] = (__bf16)ca0.w;
        af[4] = (__bf16)ca1.x; af[5] = (__bf16)ca1.y;
        af[6] = (__bf16)ca1.z; af[7] = (__bf16)ca1.w;

        acc[0] = __builtin_amdgcn_mfma_f32_16x16x32_bf16(af, vb0, acc[0], 0, 0, 0);
        acc[1] = __builtin_amdgcn_mfma_f32_16x16x32_bf16(af, vb1, acc[1], 0, 0, 0);
        acc[2] = __builtin_amdgcn_mfma_f32_16x16x32_bf16(af, vb2, acc[2], 0, 0, 0);
        acc[3] = __builtin_amdgcn_mfma_f32_16x16x32_bf16(af, vb3, acc[3], 0, 0, 0);
        acc[4] = __builtin_amdgcn_mfma_f32_16x16x32_bf16(af, vb4, acc[4], 0, 0, 0);
        acc[5] = __builtin_amdgcn_mfma_f32_16x16x32_bf16(af, vb5, acc[5], 0, 0, 0);
        acc[6] = __builtin_amdgcn_mfma_f32_16x16x32_bf16(af, vb6, acc[6], 0, 0, 0);
        acc[7] = __builtin_amdgcn_mfma_f32_16x16x32_bf16(af, vb7, acc[7], 0, 0, 0);

        ca0 = na0; ca1 = na1;
        xp += 32; wp += 32; sp += 32; vtp += 32;
    }

    // stash partial xv tiles: C/D layout (m89): col = l&15, row = (l>>4)*4 + r
#pragma unroll
    for (int c = 0; c < 8; ++c)
#pragma unroll
        for (int r = 0; r < 4; ++r)
            acc_lds[w][lg * 4 + r][c * 16 + lr] = acc[c][r];

    // fold lin/sq over the 4 k-groups (lanes differing in lg)
    lin += __shfl_xor(lin, 16); lin += __shfl_xor(lin, 32);
    sq  += __shfl_xor(sq, 16);  sq  += __shfl_xor(sq, 32);
    if (l < 16) { lin_lds[w][l] = lin; sq_lds[w][l] = sq; }
    __syncthreads();

    // combine K-split partials, then square & reduce over n
    {
        const int row = tid >> 4;        // 0..15, 16 consecutive lanes per row
        const int nc = (tid & 15) * 8;
        f32x4 v0 = (f32x4){0.f, 0.f, 0.f, 0.f};
        f32x4 v1 = (f32x4){0.f, 0.f, 0.f, 0.f};
#pragma unroll
        for (int ww = 0; ww < 4; ++ww) {
            v0 += *(const f32x4*)&acc_lds[ww][row][nc];
            v1 += *(const f32x4*)&acc_lds[ww][row][nc + 4];
        }
        float ss = dot4(v0, v0) + dot4(v1, v1);
        ss += __shfl_xor(ss, 1);
        ss += __shfl_xor(ss, 2);
        ss += __shfl_xor(ss, 4);
        ss += __shfl_xor(ss, 8);
        if ((tid & 15) == 0) {
            float linf = lin_lds[0][row] + lin_lds[1][row] + lin_lds[2][row] + lin_lds[3][row];
            float sqf  = sq_lds[0][row] + sq_lds[1][row] + sq_lds[2][row] + sq_lds[3][row];
            out[row0 + row] = linf + bptr[0] + 0.5f * (ss - sqf);
        }
    }
}

extern "C" void kernel_launch(void* const* d_in, const int* in_sizes, int n_in,
                              void* d_out, int out_size, void* d_ws, size_t ws_size,
                              hipStream_t stream) {
    const float* x = (const float*)d_in[0];
    const float* W = (const float*)d_in[1];
    const float* b = (const float*)d_in[2];
    const float* V = (const float*)d_in[3];
    float* out = (float*)d_out;

    __bf16* Vt = (__bf16*)d_ws;                                     // 128*2048*2 = 512 KB
    float* s = (float*)((char*)d_ws + 128 * 2048 * sizeof(__bf16)); // 8 KB

    fm_prep<<<32, 256, 0, stream>>>(V, Vt, s);
    fm_main<<<1024, 256, 0, stream>>>(x, W, b, Vt, s, out);
}

// Round 4
// 204.764 us; speedup vs baseline: 1.2232x; 1.2232x over previous
//
#include <hip/hip_runtime.h>
#include <hip/hip_bf16.h>

#define K_DIM 2048
#define N_DIM 128
#define BM 64
#define BK 64
#define NTILES (K_DIM / BK)        // 32
#define VT_CHUNK 16384             // 128 n * 64 k * 2B per k-chunk

typedef __bf16 bf16x8 __attribute__((ext_vector_type(8)));
typedef float f32x4 __attribute__((ext_vector_type(4)));

__device__ __forceinline__ float dot4(f32x4 a, f32x4 b) {
    return a.x * b.x + a.y * b.y + a.z * b.z + a.w * b.w;
}

__device__ __forceinline__ void gload16(const void* g, void* lds) {
    __builtin_amdgcn_global_load_lds(
        (const __attribute__((address_space(1))) unsigned int*)g,
        (__attribute__((address_space(3))) unsigned int*)lds,
        16, 0, 0);
}

// ---- prep: VtS[chunk kb][byte n*128 + ((kk*2) ^ ((n&7)<<4))] = bf16(V[kb*64+kk][n])
// (the swizzled LDS image itself, so main stages it with linear gload_lds)
// plus s[k] = sum_n V[k][n]^2
__global__ __launch_bounds__(256) void fm_prep(const float* __restrict__ V,
                                               char* __restrict__ VtS,
                                               float* __restrict__ s) {
    __shared__ float tile[64][132];
    const int t = threadIdx.x;
    const int kb = blockIdx.x;            // 32 blocks
    const int k0 = kb * 64;
#pragma unroll
    for (int i = 0; i < 8; ++i) {
        int idx = i * 256 + t;
        int kk = idx >> 5;
        int nq = (idx & 31) * 4;
        *(f32x4*)&tile[kk][nq] = *(const f32x4*)(V + (size_t)(k0 + kk) * N_DIM + nq);
    }
    __syncthreads();
    {
        const int n = t >> 1;
        const int half = t & 1;
        const int sw = (n & 7) << 4;
        char* dstbase = VtS + (size_t)kb * VT_CHUNK + n * 128;
#pragma unroll
        for (int g = 0; g < 4; ++g) {
            int kkg = half * 32 + g * 8;
            bf16x8 o;
#pragma unroll
            for (int e = 0; e < 8; ++e) o[e] = (__bf16)tile[kkg + e][n];
            *(bf16x8*)(dstbase + ((kkg * 2) ^ sw)) = o;
        }
    }
    if (t < 64) {
        float a = 0.f;
#pragma unroll
        for (int nq = 0; nq < 32; ++nq) {
            f32x4 v = *(f32x4*)&tile[t][nq * 4];
            a += dot4(v, v);
        }
        s[k0 + t] = a;
    }
}

// ---- main: block = 64 rows x 128 n x full K. 8 waves: (wr = w>>1) row-group,
// (wc = w&1) n-half. Double-buffered LDS tiles staged via global_load_lds;
// x source pre-swizzled per-lane (m173), Vt pre-swizzled in global by fm_prep.
__global__ __launch_bounds__(512, 2) void fm_main(const float* __restrict__ x,
                                                  const float* __restrict__ W,
                                                  const float* __restrict__ bptr,
                                                  const char* __restrict__ VtS,
                                                  const float* __restrict__ s,
                                                  float* __restrict__ out) {
    __shared__ __align__(16) char xbuf[2][16384];   // [64 rows][256B] swizzled
    __shared__ __align__(16) char vbuf[2][16384];   // [128 n][128B] swizzled
    __shared__ __align__(16) float Wl[2048];
    __shared__ __align__(16) float Sl[2048];
    __shared__ float lin_lds[4][16];
    __shared__ float sq_lds[4][16];
    __shared__ float ss_lds[4][2][16];

    const int tid = threadIdx.x;
    const int w = tid >> 6;
    const int l = tid & 63;
    const int lr = l & 15;
    const int lg = l >> 4;
    const int wr = w >> 1;
    const int wc = w & 1;
    const int row0 = blockIdx.x * BM;

    // W, s -> LDS (one f32x4 per thread)
    *(f32x4*)&Wl[tid * 4] = *(const f32x4*)(W + tid * 4);
    *(f32x4*)&Sl[tid * 4] = *(const f32x4*)(s + tid * 4);

    // ---- staging pointers: waves 0-3 stage x (16KB), waves 4-7 stage Vt (16KB)
    const bool isX = (w < 4);
    const char* src[4];
    int loff[4];
    if (isX) {
#pragma unroll
        for (int j = 0; j < 4; ++j) {
            int gi = w * 4 + j;                 // 0..15
            int rowt = gi * 4 + lg;             // tile row this lane stages
            int koff = (lr * 16) ^ ((rowt & 7) << 4);   // inverse-swizzled source
            src[j] = (const char*)x + (size_t)(row0 + rowt) * (K_DIM * 4) + koff;
            loff[j] = gi * 1024;
        }
    } else {
#pragma unroll
        for (int j = 0; j < 4; ++j) {
            int vi = (w - 4) * 4 + j;           // 0..15
            src[j] = VtS + vi * 1024 + l * 16;  // linear: global IS the LDS image
            loff[j] = vi * 1024;
        }
    }

    f32x4 acc[4];
#pragma unroll
    for (int c = 0; c < 4; ++c) acc[c] = (f32x4){0.f, 0.f, 0.f, 0.f};
    float lin = 0.f, sq = 0.f;

    // prologue: stage tile 0 into buf 0
    if (isX) {
#pragma unroll
        for (int j = 0; j < 4; ++j) gload16(src[j], &xbuf[0][loff[j]]);
    } else {
#pragma unroll
        for (int j = 0; j < 4; ++j) gload16(src[j], &vbuf[0][loff[j]]);
    }
    __syncthreads();

    const int rowt = wr * 16 + lr;
    const int swA = (rowt & 7) << 4;
    const char* arowbase = &xbuf[0][0] + rowt * 256;

    for (int t = 0; t < NTILES; ++t) {
        const int cur = t & 1;
        // stage next tile into the other buffer (loads stay in flight over compute)
        if (t < NTILES - 1) {
            if (isX) {
#pragma unroll
                for (int j = 0; j < 4; ++j)
                    gload16(src[j] + (size_t)(t + 1) * (BK * 4), &xbuf[cur ^ 1][loff[j]]);
            } else {
#pragma unroll
                for (int j = 0; j < 4; ++j)
                    gload16(src[j] + (size_t)(t + 1) * VT_CHUNK, &vbuf[cur ^ 1][loff[j]]);
            }
        }

        // ---- compute tile t from buf[cur]
        const char* arow = &xbuf[cur][0] + rowt * 256;
        const char* vb = &vbuf[cur][0];

        bf16x8 af[2];
        f32x4 alo[2], ahi[2];
#pragma unroll
        for (int kb = 0; kb < 2; ++kb) {
            const int kA = kb * 128 + lg * 32;
            alo[kb] = *(const f32x4*)(arow + (kA ^ swA));
            ahi[kb] = *(const f32x4*)(arow + ((kA + 16) ^ swA));
            af[kb][0] = (__bf16)alo[kb].x; af[kb][1] = (__bf16)alo[kb].y;
            af[kb][2] = (__bf16)alo[kb].z; af[kb][3] = (__bf16)alo[kb].w;
            af[kb][4] = (__bf16)ahi[kb].x; af[kb][5] = (__bf16)ahi[kb].y;
            af[kb][6] = (__bf16)ahi[kb].z; af[kb][7] = (__bf16)ahi[kb].w;
        }
        if (wc == 0) {   // one n-half owns the lin/sq accumulation (no duplicate work)
            const int ki = t * 64 + lg * 8;
#pragma unroll
            for (int kb = 0; kb < 2; ++kb) {
                f32x4 w0 = *(const f32x4*)&Wl[ki + kb * 32];
                f32x4 w1 = *(const f32x4*)&Wl[ki + kb * 32 + 4];
                f32x4 s0 = *(const f32x4*)&Sl[ki + kb * 32];
                f32x4 s1 = *(const f32x4*)&Sl[ki + kb * 32 + 4];
                lin += dot4(alo[kb], w0) + dot4(ahi[kb], w1);
                sq  += dot4(alo[kb] * alo[kb], s0) + dot4(ahi[kb] * ahi[kb], s1);
            }
        }
#pragma unroll
        for (int c = 0; c < 4; ++c) {
            const int nt = wc * 64 + c * 16 + lr;
            const int swB = (nt & 7) << 4;
            const char* brow = vb + nt * 128;
#pragma unroll
            for (int kb = 0; kb < 2; ++kb) {
                bf16x8 bf = *(const bf16x8*)(brow + ((kb * 64 + lg * 16) ^ swB));
                acc[c] = __builtin_amdgcn_mfma_f32_16x16x32_bf16(af[kb], bf, acc[c], 0, 0, 0);
            }
        }
        __syncthreads();   // next tile staged AND this tile's ds_reads drained
    }
    (void)arowbase;

    // ---- epilogue. C/D layout (m89, verified in R2): out-row = lg*4+j, out-col(n) = lr
    f32x4 vss = (f32x4){0.f, 0.f, 0.f, 0.f};
#pragma unroll
    for (int c = 0; c < 4; ++c) vss += acc[c] * acc[c];
#pragma unroll
    for (int m = 1; m < 16; m <<= 1) {
        vss.x += __shfl_xor(vss.x, m);
        vss.y += __shfl_xor(vss.y, m);
        vss.z += __shfl_xor(vss.z, m);
        vss.w += __shfl_xor(vss.w, m);
    }
    if (lr == 0) {
        ss_lds[wr][wc][lg * 4 + 0] = vss.x;
        ss_lds[wr][wc][lg * 4 + 1] = vss.y;
        ss_lds[wr][wc][lg * 4 + 2] = vss.z;
        ss_lds[wr][wc][lg * 4 + 3] = vss.w;
    }
    if (wc == 0) {
        lin += __shfl_xor(lin, 16); lin += __shfl_xor(lin, 32);
        sq  += __shfl_xor(sq, 16);  sq  += __shfl_xor(sq, 32);
        if (l < 16) { lin_lds[wr][l] = lin; sq_lds[wr][l] = sq; }
    }
    __syncthreads();
    if (tid < 64) {
        const int wrI = tid >> 4, r16 = tid & 15;
        out[row0 + tid] = lin_lds[wrI][r16] + bptr[0]
            + 0.5f * (ss_lds[wrI][0][r16] + ss_lds[wrI][1][r16] - sq_lds[wrI][r16]);
    }
}

extern "C" void kernel_launch(void* const* d_in, const int* in_sizes, int n_in,
                              void* d_out, int out_size, void* d_ws, size_t ws_size,
                              hipStream_t stream) {
    const float* x = (const float*)d_in[0];
    const float* W = (const float*)d_in[1];
    const float* b = (const float*)d_in[2];
    const float* V = (const float*)d_in[3];
    float* out = (float*)d_out;

    char* VtS = (char*)d_ws;                                  // 32 chunks * 16KB = 512KB
    float* s = (float*)((char*)d_ws + 32 * VT_CHUNK);         // 8KB

    fm_prep<<<32, 256, 0, stream>>>(V, VtS, s);
    fm_main<<<256, 512, 0, stream>>>(x, W, b, VtS, s, out);
}